// Round 1
// baseline (414.282 us; speedup 1.0000x reference)
//
#include <hip/hip_runtime.h>
#include <stdint.h>

#define NDIM 256
#define BATCH 65536
#define NROT 32640          // 256*255/2
#define PBLK 16             // parallel Givens blocks per matrix

typedef float  f32x4 __attribute__((ext_vector_type(4)));
typedef short  s16x8 __attribute__((ext_vector_type(8)));
typedef unsigned int u32x4 __attribute__((ext_vector_type(4)));
typedef unsigned int u32x2 __attribute__((ext_vector_type(2)));

// round-to-nearest-even float -> bf16 bits
static __device__ __forceinline__ unsigned short f2bf(float f) {
    unsigned int u = __float_as_uint(f);
    u += 0x7fffu + ((u >> 16) & 1u);
    return (unsigned short)(u >> 16);
}

// ---------------- workspace layout (bytes) ----------------
// cs:    2*NROT float2 (cos,sin for rots1 then rots2)   522240 B
// ping:  32 matrices of 256x256 fp32 (2 sets x 16)      8 MB
// pong:  8 MB
// abt:   512x256 bf16 (rows 0..255 = AT, 256..511 = BT) 256 KB
// invn2: BATCH fp32                                      256 KB
static constexpr size_t OFF_CS   = 0;
static constexpr size_t OFF_PING = 524288;
static constexpr size_t OFF_PONG = OFF_PING + 8388608;
static constexpr size_t OFF_ABT  = OFF_PONG + 8388608;
static constexpr size_t OFF_INV  = OFF_ABT + 262144;

// ---------------- kernel 1: cos/sin of all rotation angles ----------------
__global__ void k_cossin(const float* __restrict__ r1, const float* __restrict__ r2,
                         float2* __restrict__ cs) {
    int i = blockIdx.x * 256 + threadIdx.x;
    if (i < 2 * NROT) {
        float th = (i < NROT) ? r1[i] : r2[i - NROT];
        cs[i] = make_float2(cosf(th), sinf(th));
    }
}

// ---------------- kernel 2: build PBLK partial Givens products per matrix ----
// Block b covers a sweep-aligned range of rotations; one thread per column,
// column state in LDS, row i of the active sweep held in a register (u).
// No barriers needed: each thread touches only its own column.
__global__ __launch_bounds__(64) void k_blocks(const float2* __restrict__ cs,
                                               float* __restrict__ bmats) {
    __shared__ float colb[256 * 64];
    const int t = threadIdx.x;          // column within chunk
    const int chunk = blockIdx.x;       // 0..3 (64 cols each)
    const int b = blockIdx.y;           // block 0..15
    const int set = blockIdx.z;         // 0 = rots1, 1 = rots2
    const int col0 = chunk * 64;

    // sweep-aligned partition boundaries: cum(i) = #rotations before sweep i
    const int tlo = b * (NROT / PBLK);
    const int thi = (b + 1) * (NROT / PBLK);
    int s0 = -1, s1 = -1, roff = 0;
    {
        int cum = 0;
        for (int i = 0; i <= 255; i++) {
            if (s0 < 0 && cum >= tlo) { s0 = i; roff = cum; }
            if (s1 < 0 && cum >= thi) { s1 = i; }
            cum += 255 - i;
        }
        if (s1 < 0) s1 = 255;
    }

    // init identity (this WG's 64 columns)
    for (int r = 0; r < 256; r++)
        colb[r * 64 + t] = (r == col0 + t) ? 1.0f : 0.0f;

    const float2* mycs = cs + (size_t)set * NROT + roff;
    for (int i = s0; i < s1; i++) {
        float u = colb[i * 64 + t];
        #pragma unroll 4
        for (int j = i + 1; j < 256; j++) {
            float2 cv = *mycs++;
            float rj = colb[j * 64 + t];
            colb[j * 64 + t] = cv.y * u + cv.x * rj;   // new row j (uses old u)
            u = cv.x * u - cv.y * rj;                  // new row i (uses old rj)
        }
        colb[i * 64 + t] = u;
    }

    float* outm = bmats + (size_t)(set * PBLK + b) * 65536;
    for (int r = 0; r < 256; r++)
        outm[(size_t)r * 256 + col0 + t] = colb[r * 64 + t];
}

// ---------------- kernel 3: pairwise combine round (fp32 256^3 matmul) ------
// dst[p] = src[2p+1] @ src[2p]  (later block on the left), per set.
__global__ __launch_bounds__(256) void k_combine(const float* __restrict__ src,
                                                 float* __restrict__ dst, int half) {
    const int by = blockIdx.y;
    const int set = by / half, pidx = by % half;
    const float* Am = src + (size_t)(set * 2 * half + 2 * pidx + 1) * 65536;
    const float* Bm = src + (size_t)(set * 2 * half + 2 * pidx) * 65536;
    float* Dm = dst + (size_t)(set * half + pidx) * 65536;
    const int tr = blockIdx.x >> 2, tc = blockIdx.x & 3;

    __shared__ float As[64 * 32];
    __shared__ float Bs[32 * 64];
    const int tid = threadIdx.x;
    const int tx = tid & 15, ty = tid >> 4;

    float acc[4][4] = {};
    for (int kb = 0; kb < 8; kb++) {
        __syncthreads();
        #pragma unroll
        for (int it = 0; it < 2; it++) {           // A: 64x32 = 512 float4
            int flat = tid + it * 256;
            int r = flat >> 3, c4 = flat & 7;
            f32x4 v = *(const f32x4*)&Am[(size_t)(tr * 64 + r) * 256 + kb * 32 + c4 * 4];
            *(f32x4*)&As[r * 32 + c4 * 4] = v;
        }
        #pragma unroll
        for (int it = 0; it < 2; it++) {           // B: 32x64 = 512 float4
            int flat = tid + it * 256;
            int r = flat >> 4, c4 = flat & 15;
            f32x4 v = *(const f32x4*)&Bm[(size_t)(kb * 32 + r) * 256 + tc * 64 + c4 * 4];
            *(f32x4*)&Bs[r * 64 + c4 * 4] = v;
        }
        __syncthreads();
        #pragma unroll 8
        for (int kk = 0; kk < 32; kk++) {
            f32x4 bv = *(const f32x4*)&Bs[kk * 64 + tx * 4];
            float a0 = As[(ty * 4 + 0) * 32 + kk];
            float a1 = As[(ty * 4 + 1) * 32 + kk];
            float a2 = As[(ty * 4 + 2) * 32 + kk];
            float a3 = As[(ty * 4 + 3) * 32 + kk];
            #pragma unroll
            for (int j = 0; j < 4; j++) {
                acc[0][j] += a0 * bv[j];
                acc[1][j] += a1 * bv[j];
                acc[2][j] += a2 * bv[j];
                acc[3][j] += a3 * bv[j];
            }
        }
    }
    #pragma unroll
    for (int i = 0; i < 4; i++) {
        f32x4 v = { acc[i][0], acc[i][1], acc[i][2], acc[i][3] };
        *(f32x4*)&Dm[(size_t)(tr * 64 + ty * 4 + i) * 256 + tc * 64 + tx * 4] = v;
    }
}

// ---------------- kernel 4: AT/BT = M2 @ diag(cos|sin(phases)) @ M1 -> bf16 -
__global__ __launch_bounds__(256) void k_abt(const float* __restrict__ mats,
                                             const float* __restrict__ phases,
                                             unsigned short* __restrict__ abt) {
    const float* Am = mats + 65536;    // M2
    const float* Bm = mats;            // M1
    const int v = blockIdx.y;          // 0: cos (AT), 1: sin (BT)
    const int tr = blockIdx.x >> 2, tc = blockIdx.x & 3;

    __shared__ float As[64 * 32];
    __shared__ float Bs[32 * 64];
    const int tid = threadIdx.x;
    const int tx = tid & 15, ty = tid >> 4;

    float acc[4][4] = {};
    for (int kb = 0; kb < 8; kb++) {
        __syncthreads();
        #pragma unroll
        for (int it = 0; it < 2; it++) {
            int flat = tid + it * 256;
            int r = flat >> 3, c4 = flat & 7;
            f32x4 vv = *(const f32x4*)&Am[(size_t)(tr * 64 + r) * 256 + kb * 32 + c4 * 4];
            *(f32x4*)&As[r * 32 + c4 * 4] = vv;
        }
        #pragma unroll
        for (int it = 0; it < 2; it++) {
            int flat = tid + it * 256;
            int r = flat >> 4, c4 = flat & 15;
            int kg = kb * 32 + r;
            float ph = phases[kg];
            float sc = v ? sinf(ph) : cosf(ph);
            f32x4 vv = *(const f32x4*)&Bm[(size_t)kg * 256 + tc * 64 + c4 * 4];
            vv[0] *= sc; vv[1] *= sc; vv[2] *= sc; vv[3] *= sc;
            *(f32x4*)&Bs[r * 64 + c4 * 4] = vv;
        }
        __syncthreads();
        #pragma unroll 8
        for (int kk = 0; kk < 32; kk++) {
            f32x4 bv = *(const f32x4*)&Bs[kk * 64 + tx * 4];
            float a0 = As[(ty * 4 + 0) * 32 + kk];
            float a1 = As[(ty * 4 + 1) * 32 + kk];
            float a2 = As[(ty * 4 + 2) * 32 + kk];
            float a3 = As[(ty * 4 + 3) * 32 + kk];
            #pragma unroll
            for (int j = 0; j < 4; j++) {
                acc[0][j] += a0 * bv[j];
                acc[1][j] += a1 * bv[j];
                acc[2][j] += a2 * bv[j];
                acc[3][j] += a3 * bv[j];
            }
        }
    }
    #pragma unroll
    for (int i = 0; i < 4; i++) {
        unsigned short h0 = f2bf(acc[i][0]), h1 = f2bf(acc[i][1]);
        unsigned short h2 = f2bf(acc[i][2]), h3 = f2bf(acc[i][3]);
        u32x2 pk = { (unsigned)h0 | ((unsigned)h1 << 16),
                     (unsigned)h2 | ((unsigned)h3 << 16) };
        *(u32x2*)&abt[(size_t)(v * 256 + tr * 64 + ty * 4 + i) * 256 + tc * 64 + tx * 4] = pk;
    }
}

// ---------------- kernel 5: per-row 1/||x||^2 -------------------------------
__global__ __launch_bounds__(256) void k_norm(const float* __restrict__ x,
                                              float* __restrict__ invn2) {
    const int row = blockIdx.x * 4 + (threadIdx.x >> 6);
    const int lane = threadIdx.x & 63;
    f32x4 v = *(const f32x4*)&x[(size_t)row * 256 + lane * 4];
    float s = v[0] * v[0] + v[1] * v[1] + v[2] * v[2] + v[3] * v[3];
    for (int off = 32; off; off >>= 1) s += __shfl_xor(s, off, 64);
    if (lane == 0) invn2[row] = 1.0f / s;
}

// ---------------- kernel 6: final fused GEMM + |.|^2 epilogue ---------------
// out[r][t] = (p^2 + q^2) * invn2[r],  p = x_r . AT_t,  q = x_r . BT_t
// Tile: 128 rows x 64 out-cols per WG (acc-n = 128: p-cols 0..63, q-cols 64..127)
// 4 waves, each 32 rows x 128 n; MFMA 16x16x32 bf16.
#define BKP 136   // padded LDS k-stride (bf16 elems): +8 keeps 16B align, 2-way banks
__global__ __launch_bounds__(256) void k_gemm(const float* __restrict__ x,
                                              const unsigned short* __restrict__ abt,
                                              const float* __restrict__ invn2,
                                              float* __restrict__ out) {
    __shared__ unsigned short As[128 * BKP];
    __shared__ unsigned short Bs[128 * BKP];
    const int tid = threadIdx.x;
    const int cb = blockIdx.x;          // 0..3  (64 out-cols each)
    const int rb = blockIdx.y;          // 0..511
    const int lane = tid & 63, w = tid >> 6;

    f32x4 acc[16];
    #pragma unroll
    for (int i = 0; i < 16; i++) acc[i] = (f32x4){0.f, 0.f, 0.f, 0.f};

    for (int kb = 0; kb < 2; kb++) {
        __syncthreads();
        // stage x tile (128x128 fp32 -> bf16)
        #pragma unroll
        for (int it = 0; it < 16; it++) {
            int flat = tid + it * 256;            // 128 rows x 32 float4
            int r = flat >> 5, c4 = flat & 31;
            f32x4 v = *(const f32x4*)&x[(size_t)(rb * 128 + r) * 256 + kb * 128 + c4 * 4];
            unsigned short h0 = f2bf(v[0]), h1 = f2bf(v[1]);
            unsigned short h2 = f2bf(v[2]), h3 = f2bf(v[3]);
            u32x2 pk = { (unsigned)h0 | ((unsigned)h1 << 16),
                         (unsigned)h2 | ((unsigned)h3 << 16) };
            *(u32x2*)&As[r * BKP + c4 * 4] = pk;
        }
        // stage Bt tile: rows 0..63 from AT[cb*64..], rows 64..127 from BT[cb*64..]
        #pragma unroll
        for (int it = 0; it < 8; it++) {
            int flat = tid + it * 256;            // 128 rows x 16 chunks(8 bf16)
            int r = flat >> 4, c8 = flat & 15;
            int gr = (r < 64) ? (cb * 64 + r) : (256 + cb * 64 + (r - 64));
            u32x4 vv = *(const u32x4*)&abt[(size_t)gr * 256 + kb * 128 + c8 * 8];
            *(u32x4*)&Bs[r * BKP + c8 * 8] = vv;
        }
        __syncthreads();
        #pragma unroll
        for (int ks = 0; ks < 4; ks++) {
            const int k0 = ks * 32 + (lane >> 4) * 8;
            s16x8 a[2], b[8];
            #pragma unroll
            for (int tm = 0; tm < 2; tm++)
                a[tm] = *(const s16x8*)&As[(w * 32 + tm * 16 + (lane & 15)) * BKP + k0];
            #pragma unroll
            for (int tn = 0; tn < 8; tn++)
                b[tn] = *(const s16x8*)&Bs[(tn * 16 + (lane & 15)) * BKP + k0];
            #pragma unroll
            for (int tm = 0; tm < 2; tm++)
                #pragma unroll
                for (int tn = 0; tn < 8; tn++)
                    acc[tm * 8 + tn] = __builtin_amdgcn_mfma_f32_16x16x32_bf16(
                        a[tm], b[tn], acc[tm * 8 + tn], 0, 0, 0);
        }
    }

    // epilogue: C/D layout col = lane&15, row = (lane>>4)*4 + reg
    const int qr = lane >> 4, c = lane & 15;
    #pragma unroll
    for (int tm = 0; tm < 2; tm++) {
        float inv[4];
        #pragma unroll
        for (int r = 0; r < 4; r++)
            inv[r] = invn2[rb * 128 + w * 32 + tm * 16 + qr * 4 + r];
        #pragma unroll
        for (int tn = 0; tn < 4; tn++) {
            f32x4 p = acc[tm * 8 + tn];
            f32x4 q = acc[tm * 8 + tn + 4];
            #pragma unroll
            for (int r = 0; r < 4; r++) {
                int m = w * 32 + tm * 16 + qr * 4 + r;
                out[(size_t)(rb * 128 + m) * 256 + cb * 64 + tn * 16 + c] =
                    (p[r] * p[r] + q[r] * q[r]) * inv[r];
            }
        }
    }
}

// ---------------- host ------------------------------------------------------
extern "C" void kernel_launch(void* const* d_in, const int* in_sizes, int n_in,
                              void* d_out, int out_size, void* d_ws, size_t ws_size,
                              hipStream_t stream) {
    (void)in_sizes; (void)n_in; (void)out_size; (void)ws_size;
    const float* x      = (const float*)d_in[0];
    const float* rots1  = (const float*)d_in[1];
    const float* phases = (const float*)d_in[2];
    const float* rots2  = (const float*)d_in[3];
    float* out = (float*)d_out;
    char* ws = (char*)d_ws;

    float2*         cs    = (float2*)(ws + OFF_CS);
    float*          ping  = (float*)(ws + OFF_PING);
    float*          pong  = (float*)(ws + OFF_PONG);
    unsigned short* abt   = (unsigned short*)(ws + OFF_ABT);
    float*          invn2 = (float*)(ws + OFF_INV);

    k_cossin<<<(2 * NROT + 255) / 256, 256, 0, stream>>>(rots1, rots2, cs);
    k_blocks<<<dim3(4, PBLK, 2), 64, 0, stream>>>(cs, ping);
    k_combine<<<dim3(16, 16), 256, 0, stream>>>(ping, pong, 8);  // 16 -> 8 per set
    k_combine<<<dim3(16, 8),  256, 0, stream>>>(pong, ping, 4);  // 8 -> 4
    k_combine<<<dim3(16, 4),  256, 0, stream>>>(ping, pong, 2);  // 4 -> 2
    k_combine<<<dim3(16, 2),  256, 0, stream>>>(pong, ping, 1);  // 2 -> 1 (M1, M2)
    k_abt<<<dim3(16, 2), 256, 0, stream>>>(ping, phases, abt);
    k_norm<<<BATCH / 4, 256, 0, stream>>>(x, invn2);
    k_gemm<<<dim3(4, BATCH / 128), 256, 0, stream>>>(x, abt, invn2, out);
}